// Round 10
// baseline (1669.985 us; speedup 1.0000x reference)
//
#include <hip/hip_runtime.h>
#include <hip/hip_bf16.h>
#include <math.h>

#define HID 32
#define HIDW 16    // u32 words per node row (bf16x2)
#define POOLW 192  // 6 layers * 32
#define NBMAX 1600 // max buckets (64-node buckets, n<=102400)
#define ECHUNK 8192
#define STAGE 1280 // staged edges per chunk (bucket avg ~1024)
#define ACCW 33    // padded row stride (bank-conflict-free LDS atomics)

typedef __hip_bfloat16 bf16;

__device__ __forceinline__ float bf_lo(unsigned w) {
    union { unsigned u; float f; } c; c.u = w << 16; return c.f;
}
__device__ __forceinline__ float bf_hi(unsigned w) {
    union { unsigned u; float f; } c; c.u = w & 0xFFFF0000u; return c.f;
}

// ---------- bucket-level histogram (LDS-aggregated), buckets of 64 dst ----------
__global__ __launch_bounds__(256) void k_bcount(const int* __restrict__ dst,
                                                int* __restrict__ bcount, int E, int NB) {
    __shared__ int hist[NBMAX];
    int t = threadIdx.x;
    int e0 = blockIdx.x * ECHUNK;
    int e1 = min(e0 + ECHUNK, E);
    for (int k = t; k < NB; k += 256) hist[k] = 0;
    __syncthreads();
    for (int e = e0 + t; e < e1; e += 256) atomicAdd(&hist[dst[e] >> 6], 1);
    __syncthreads();
    for (int k = t; k < NB; k += 256) {
        int c = hist[k];
        if (c > 0) atomicAdd(&bcount[k], c);
    }
}

// ---------- single-block exclusive scan of bucket counts (NB <= 2048) ----------
__global__ __launch_bounds__(256) void k_bscan(const int* __restrict__ bcount,
                                               int* __restrict__ bstart,
                                               int* __restrict__ bcur, int NB) {
    __shared__ int sh[256];
    int t = threadIdx.x;
    int base = t * 8;
    int v[8]; int s = 0;
#pragma unroll
    for (int i = 0; i < 8; ++i) { v[i] = (base + i < NB) ? bcount[base + i] : 0; s += v[i]; }
    sh[t] = s;
    __syncthreads();
    for (int off = 1; off < 256; off <<= 1) {
        int xv = (t >= off) ? sh[t - off] : 0;
        __syncthreads();
        sh[t] += xv;
        __syncthreads();
    }
    int run = sh[t] - s;
#pragma unroll
    for (int i = 0; i < 8; ++i) {
        if (base + i < NB) { bstart[base + i] = run; bcur[base + i] = run; }
        run += v[i];
    }
    if (t == 255) bstart[NB] = run;
}

// ---------- phase 1: block-aggregated binning into bucket windows ----------
// packed payload: src (17 bits) | local_dst (6 bits) << 17
__global__ __launch_bounds__(256) void k_bin(const int* __restrict__ src,
                                             const int* __restrict__ dst,
                                             int* __restrict__ bcur,
                                             unsigned* __restrict__ tmp,
                                             int E, int NB) {
    __shared__ int hist[NBMAX];
    int t = threadIdx.x;
    int e0 = blockIdx.x * ECHUNK;
    int e1 = min(e0 + ECHUNK, E);
    for (int k = t; k < NB; k += 256) hist[k] = 0;
    __syncthreads();
    for (int e = e0 + t; e < e1; e += 256) atomicAdd(&hist[dst[e] >> 6], 1);
    __syncthreads();
    for (int k = t; k < NB; k += 256) {
        int c = hist[k];
        hist[k] = (c > 0) ? atomicAdd(&bcur[k], c) : 0;
    }
    __syncthreads();
    for (int e = e0 + t; e < e1; e += 256) {
        int s = src[e], d = dst[e];
        int p = atomicAdd(&hist[d >> 6], 1);
        tmp[p] = (unsigned)s | ((unsigned)(d & 63) << 17);
    }
}

// ---------- per bucket: degree -> dinv, xs = dinv*x ----------
__global__ __launch_bounds__(256) void k_deg(const unsigned* __restrict__ tmp,
                                             const int* __restrict__ bstart,
                                             const float* __restrict__ x,
                                             float* __restrict__ dinv,
                                             float* __restrict__ xs, int n) {
    __shared__ int cnt[64];
    int b = blockIdx.x;
    int node0 = b << 6;
    int nn = min(64, n - node0);
    int t = threadIdx.x;
    int base = bstart[b];
    int count = bstart[b + 1] - base;
    if (t < 64) cnt[t] = 0;
    __syncthreads();
    for (int k = t; k < count; k += 256) atomicAdd(&cnt[tmp[base + k] >> 17], 1);
    __syncthreads();
    if (t < nn) {
        float di = rsqrtf((float)(cnt[t] + 1));
        dinv[node0 + t] = di;
        xs[node0 + t] = di * x[node0 + t];
    }
}

// ---------- layer 0: edge-parallel scalar gather + pool + transform ----------
__global__ __launch_bounds__(256) void k_layer0(
        const unsigned* __restrict__ tmp, const int* __restrict__ bstart,
        const float* __restrict__ xs, unsigned* __restrict__ Tout,
        const float* __restrict__ dinv, const float* __restrict__ b1,
        const float* __restrict__ W1, const float* __restrict__ W2,
        const int* __restrict__ batch, float* __restrict__ pooled, int n) {
    __shared__ float acc1[64];
    __shared__ unsigned stage[STAGE];
    __shared__ float wsh[HID * HID];
    __shared__ float hred[16][HID];
    __shared__ int gid[16];
    int b = blockIdx.x;
    int node0 = b << 6;
    int t = threadIdx.x;
    int base = bstart[b];
    int count = bstart[b + 1] - base;
    int il = t >> 4, jp = t & 15;

    for (int k = t; k < HID * HID; k += 256) wsh[k] = W2[k];
    if (t < 64) acc1[t] = 0.f;

    for (int c0 = 0; c0 < count; c0 += STAGE) {
        int cc = min(STAGE, count - c0);
        __syncthreads();
        for (int k = t; k < cc; k += 256) stage[k] = tmp[base + c0 + k];
        __syncthreads();
        int e = t;
        for (; e + 768 < cc; e += 1024) {
            unsigned v0 = stage[e], v1 = stage[e + 256], v2 = stage[e + 512], v3 = stage[e + 768];
            float x0 = xs[v0 & 0x1FFFF], x1 = xs[v1 & 0x1FFFF];
            float x2 = xs[v2 & 0x1FFFF], x3 = xs[v3 & 0x1FFFF];
            atomicAdd(&acc1[v0 >> 17], x0);
            atomicAdd(&acc1[v1 >> 17], x1);
            atomicAdd(&acc1[v2 >> 17], x2);
            atomicAdd(&acc1[v3 >> 17], x3);
        }
        for (; e < cc; e += 256) {
            unsigned v = stage[e];
            atomicAdd(&acc1[v >> 17], xs[v & 0x1FFFF]);
        }
    }
    __syncthreads();

    float w1l = W1[2 * jp], w1h = W1[2 * jp + 1];
    float b1l = b1[2 * jp], b1h = b1[2 * jp + 1];
    for (int p = 0; p < 4; ++p) {
        int node = node0 + p * 16 + il;
        bool valid = node < n;
        float lo = 0.f, hi = 0.f, di = 0.f;
        if (valid) {
            di = dinv[node];
            float tot = di * (acc1[p * 16 + il] + xs[node]);  // + self loop
            lo = fmaxf(tot * w1l + b1l, 0.f);
            hi = fmaxf(tot * w1h + b1h, 0.f);
        }
        hred[il][2 * jp] = lo;
        hred[il][2 * jp + 1] = hi;
        if (jp == 0) gid[il] = valid ? batch[node] : -1;
        __syncthreads();
        if (t < HID) {
            float run = 0.f;
            int g = gid[0];
#pragma unroll
            for (int q = 0; q < 16; ++q) {
                int gn = gid[q];
                if (gn != g) {
                    if (g >= 0) atomicAdd(&pooled[g * POOLW + t], run);
                    run = 0.f;
                    g = gn;
                }
                run += hred[q][t];
            }
            if (g >= 0) atomicAdd(&pooled[g * POOLW + t], run);
        }
        if (valid) {
            float al = 0.f, ah = 0.f;
#pragma unroll
            for (int k = 0; k < HID; ++k) {
                float hh = hred[il][k];
                al += hh * wsh[k * HID + 2 * jp];
                ah += hh * wsh[k * HID + 2 * jp + 1];
            }
            union { bf16 bb[2]; unsigned u; } pk;
            pk.bb[0] = __float2bfloat16(di * al);
            pk.bb[1] = __float2bfloat16(di * ah);
            Tout[node * HIDW + jp] = pk.u;
        }
        __syncthreads();
    }
}

// ---------- layers 1..5: edge-parallel gather into LDS acc + pool + transform ----------
// one block per 64-node bucket; 16-lane groups stream independent edges.
__global__ __launch_bounds__(256) void k_layer(
        const unsigned* __restrict__ tmp, const int* __restrict__ bstart,
        const unsigned* __restrict__ Tin, unsigned* __restrict__ Tout,
        const float* __restrict__ dinv, const float* __restrict__ bias,
        const float* __restrict__ Wnext, const int* __restrict__ batch,
        float* __restrict__ pooled, int n, int layer, int last) {
    __shared__ float acc[64 * ACCW];
    __shared__ unsigned stage[STAGE];
    __shared__ float wsh[HID * HID];
    __shared__ int gid[16];
    int b = blockIdx.x;
    int node0 = b << 6;
    int t = threadIdx.x;
    int base = bstart[b];
    int count = bstart[b + 1] - base;
    int g16 = t >> 4, jp = t & 15;

    if (!last) {
        for (int k = t; k < HID * HID; k += 256) wsh[k] = Wnext[k];
    }
    for (int k = t; k < 64 * ACCW; k += 256) acc[k] = 0.f;

    for (int c0 = 0; c0 < count; c0 += STAGE) {
        int cc = min(STAGE, count - c0);
        __syncthreads();
        for (int k = t; k < cc; k += 256) stage[k] = tmp[base + c0 + k];
        __syncthreads();
        int e = g16;
        for (; e + 112 < cc; e += 128) {
            unsigned v0 = stage[e],      v1 = stage[e + 16], v2 = stage[e + 32], v3 = stage[e + 48];
            unsigned v4 = stage[e + 64], v5 = stage[e + 80], v6 = stage[e + 96], v7 = stage[e + 112];
            unsigned w0 = Tin[(v0 & 0x1FFFF) * HIDW + jp], w1 = Tin[(v1 & 0x1FFFF) * HIDW + jp];
            unsigned w2 = Tin[(v2 & 0x1FFFF) * HIDW + jp], w3 = Tin[(v3 & 0x1FFFF) * HIDW + jp];
            unsigned w4 = Tin[(v4 & 0x1FFFF) * HIDW + jp], w5 = Tin[(v5 & 0x1FFFF) * HIDW + jp];
            unsigned w6 = Tin[(v6 & 0x1FFFF) * HIDW + jp], w7 = Tin[(v7 & 0x1FFFF) * HIDW + jp];
            atomicAdd(&acc[(v0 >> 17) * ACCW + 2 * jp], bf_lo(w0));
            atomicAdd(&acc[(v0 >> 17) * ACCW + 2 * jp + 1], bf_hi(w0));
            atomicAdd(&acc[(v1 >> 17) * ACCW + 2 * jp], bf_lo(w1));
            atomicAdd(&acc[(v1 >> 17) * ACCW + 2 * jp + 1], bf_hi(w1));
            atomicAdd(&acc[(v2 >> 17) * ACCW + 2 * jp], bf_lo(w2));
            atomicAdd(&acc[(v2 >> 17) * ACCW + 2 * jp + 1], bf_hi(w2));
            atomicAdd(&acc[(v3 >> 17) * ACCW + 2 * jp], bf_lo(w3));
            atomicAdd(&acc[(v3 >> 17) * ACCW + 2 * jp + 1], bf_hi(w3));
            atomicAdd(&acc[(v4 >> 17) * ACCW + 2 * jp], bf_lo(w4));
            atomicAdd(&acc[(v4 >> 17) * ACCW + 2 * jp + 1], bf_hi(w4));
            atomicAdd(&acc[(v5 >> 17) * ACCW + 2 * jp], bf_lo(w5));
            atomicAdd(&acc[(v5 >> 17) * ACCW + 2 * jp + 1], bf_hi(w5));
            atomicAdd(&acc[(v6 >> 17) * ACCW + 2 * jp], bf_lo(w6));
            atomicAdd(&acc[(v6 >> 17) * ACCW + 2 * jp + 1], bf_hi(w6));
            atomicAdd(&acc[(v7 >> 17) * ACCW + 2 * jp], bf_lo(w7));
            atomicAdd(&acc[(v7 >> 17) * ACCW + 2 * jp + 1], bf_hi(w7));
        }
        for (; e < cc; e += 16) {
            unsigned v = stage[e];
            unsigned w = Tin[(v & 0x1FFFF) * HIDW + jp];
            atomicAdd(&acc[(v >> 17) * ACCW + 2 * jp], bf_lo(w));
            atomicAdd(&acc[(v >> 17) * ACCW + 2 * jp + 1], bf_hi(w));
        }
    }
    __syncthreads();

    int il = g16;
    float bl = bias[2 * jp], bh = bias[2 * jp + 1];
    for (int p = 0; p < 4; ++p) {
        int node = node0 + p * 16 + il;
        bool valid = node < n;
        float di = 0.f;
        if (valid) {
            di = dinv[node];
            unsigned w = Tin[node * HIDW + jp];  // self loop
            int ld = p * 16 + il;
            float accl = acc[ld * ACCW + 2 * jp] + bf_lo(w);
            float acch = acc[ld * ACCW + 2 * jp + 1] + bf_hi(w);
            float lo = fmaxf(di * accl + bl, 0.f);
            float hi = fmaxf(di * acch + bh, 0.f);
            acc[ld * ACCW + 2 * jp] = lo;      // h in place
            acc[ld * ACCW + 2 * jp + 1] = hi;
        }
        if (jp == 0) gid[il] = valid ? batch[node] : -1;
        __syncthreads();
        if (t < HID) {
            float run = 0.f;
            int g = gid[0];
#pragma unroll
            for (int q = 0; q < 16; ++q) {
                int gn = gid[q];
                if (gn != g) {
                    if (g >= 0) atomicAdd(&pooled[g * POOLW + layer * HID + t], run);
                    run = 0.f;
                    g = gn;
                }
                run += acc[(p * 16 + q) * ACCW + t];
            }
            if (g >= 0) atomicAdd(&pooled[g * POOLW + layer * HID + t], run);
        }
        if (!last && valid) {
            float al = 0.f, ah = 0.f;
#pragma unroll
            for (int k = 0; k < HID; ++k) {
                float hh = acc[(p * 16 + il) * ACCW + k];
                al += hh * wsh[k * HID + 2 * jp];
                ah += hh * wsh[k * HID + 2 * jp + 1];
            }
            union { bf16 bb[2]; unsigned u; } pk;
            pk.bb[0] = __float2bfloat16(di * al);
            pk.bb[1] = __float2bfloat16(di * ah);
            Tout[node * HIDW + jp] = pk.u;
        }
        __syncthreads();
    }
}

// ---------- head: fc1(192->128) + relu + fc2(128->2) + softmax ----------
__global__ __launch_bounds__(128) void k_mlp(const float* __restrict__ pooled,
                                             const float* __restrict__ fc1_w,
                                             const float* __restrict__ fc1_b,
                                             const float* __restrict__ fc2_w,
                                             const float* __restrict__ fc2_b,
                                             float* __restrict__ out, int G) {
    __shared__ float z[POOLW];
    __shared__ float w0s[2], w1s[2];
    int g = blockIdx.x;
    int t = threadIdx.x;
    for (int k = t; k < POOLW; k += 128) z[k] = pooled[g * POOLW + k];
    __syncthreads();
    float a = fc1_b[t];
    for (int k = 0; k < POOLW; ++k) a += z[k] * fc1_w[k * 128 + t];
    float z1 = fmaxf(a, 0.f);
    float p0 = z1 * fc2_w[t * 2 + 0];
    float p1 = z1 * fc2_w[t * 2 + 1];
    for (int off = 32; off >= 1; off >>= 1) {
        p0 += __shfl_down(p0, off, 64);
        p1 += __shfl_down(p1, off, 64);
    }
    if ((t & 63) == 0) { w0s[t >> 6] = p0; w1s[t >> 6] = p1; }
    __syncthreads();
    if (t == 0) {
        float o0 = w0s[0] + w0s[1] + fc2_b[0];
        float o1 = w1s[0] + w1s[1] + fc2_b[1];
        float m = fmaxf(o0, o1);
        float e0 = expf(o0 - m), e1 = expf(o1 - m);
        float s = e0 + e1;
        out[g * 2 + 0] = e0 / s;
        out[g * 2 + 1] = e1 / s;
    }
}

extern "C" void kernel_launch(void* const* d_in, const int* in_sizes, int n_in,
                              void* d_out, int out_size, void* d_ws, size_t ws_size,
                              hipStream_t stream) {
    const float* x     = (const float*)d_in[0];
    const int*   ei    = (const int*)d_in[1];
    const int*   batch = (const int*)d_in[2];
    const float* Ws[6] = {(const float*)d_in[3], (const float*)d_in[5],
                          (const float*)d_in[7], (const float*)d_in[9],
                          (const float*)d_in[11], (const float*)d_in[13]};
    const float* bs[6] = {(const float*)d_in[4], (const float*)d_in[6],
                          (const float*)d_in[8], (const float*)d_in[10],
                          (const float*)d_in[12], (const float*)d_in[14]};
    const float* fc1_w = (const float*)d_in[15];
    const float* fc1_b = (const float*)d_in[16];
    const float* fc2_w = (const float*)d_in[17];
    const float* fc2_b = (const float*)d_in[18];

    int n = in_sizes[0];       // 100000
    int E = in_sizes[1] / 2;   // 1600000
    int G = out_size / 2;      // 256
    const int* src = ei;
    const int* dst = ei + E;
    int NB = (n + 63) / 64;    // 64-node buckets (1563)

    char* p = (char*)d_ws;
    auto alloc = [&](size_t bytes) -> void* {
        void* r = (void*)p;
        p += (bytes + 255) / 256 * 256;
        return r;
    };
    int*      bcount = (int*)alloc((size_t)NB * 4);
    int*      bstart = (int*)alloc((size_t)(NB + 1) * 4);
    int*      bcur   = (int*)alloc((size_t)NB * 4);
    float*    dinv   = (float*)alloc((size_t)n * 4);
    float*    xs     = (float*)alloc((size_t)n * 4);
    unsigned* tmp    = (unsigned*)alloc((size_t)E * 4);
    unsigned* Ta     = (unsigned*)alloc((size_t)n * HIDW * 4);
    unsigned* Tb     = (unsigned*)alloc((size_t)n * HIDW * 4);
    float*    pooled = (float*)alloc((size_t)G * POOLW * 4);

    hipMemsetAsync(bcount, 0, (size_t)NB * 4, stream);
    hipMemsetAsync(pooled, 0, (size_t)G * POOLW * 4, stream);

    int nbE = (E + ECHUNK - 1) / ECHUNK;
    k_bcount<<<nbE, 256, 0, stream>>>(dst, bcount, E, NB);
    k_bscan<<<1, 256, 0, stream>>>(bcount, bstart, bcur, NB);
    k_bin<<<nbE, 256, 0, stream>>>(src, dst, bcur, tmp, E, NB);
    k_deg<<<NB, 256, 0, stream>>>(tmp, bstart, x, dinv, xs, n);

    // layer 0 (scalar, edge-parallel) writes T for layer 1 into Tb
    k_layer0<<<NB, 256, 0, stream>>>(tmp, bstart, xs, Tb, dinv, bs[0],
                                     Ws[0], Ws[1], batch, pooled, n);
    unsigned* Tin = Tb;
    unsigned* Tout = Ta;
    for (int l = 1; l < 6; ++l) {
        int last = (l == 5);
        k_layer<<<NB, 256, 0, stream>>>(tmp, bstart, Tin, Tout, dinv, bs[l],
                                        last ? nullptr : Ws[l + 1], batch,
                                        pooled, n, l, last);
        unsigned* t2 = Tin; Tin = Tout; Tout = t2;
    }
    k_mlp<<<G, 128, 0, stream>>>(pooled, fc1_w, fc1_b, fc2_w, fc2_b, (float*)d_out, G);
}

// Round 11
// 217.678 us; speedup vs baseline: 7.6718x; 7.6718x over previous
//
#include <hip/hip_runtime.h>
#include <hip/hip_bf16.h>
#include <math.h>

#define HID 32
#define HIDW 16   // u32 words per node row (bf16x2)
#define POOLW 192 // 6 layers * 32
#define CAP 3072  // max edges per 128-node bucket (avg ~2048)
#define NBMAX 800 // max buckets (n<=102400)
#define ECHUNK 8192

typedef __hip_bfloat16 bf16;

__device__ __forceinline__ float bf_lo(unsigned w) {
    union { unsigned u; float f; } c; c.u = w << 16; return c.f;
}
__device__ __forceinline__ float bf_hi(unsigned w) {
    union { unsigned u; float f; } c; c.u = w & 0xFFFF0000u; return c.f;
}

// ---------- bucket-level histogram (LDS-aggregated) ----------
__global__ __launch_bounds__(256) void k_bcount(const int* __restrict__ dst,
                                                int* __restrict__ bcount, int E, int NB) {
    __shared__ int hist[NBMAX];
    int t = threadIdx.x;
    int e0 = blockIdx.x * ECHUNK;
    int e1 = min(e0 + ECHUNK, E);
    for (int k = t; k < NB; k += 256) hist[k] = 0;
    __syncthreads();
    for (int e = e0 + t; e < e1; e += 256) atomicAdd(&hist[dst[e] >> 7], 1);
    __syncthreads();
    for (int k = t; k < NB; k += 256) {
        int c = hist[k];
        if (c > 0) atomicAdd(&bcount[k], c);
    }
}

// ---------- single-block exclusive scan of bucket counts ----------
__global__ __launch_bounds__(256) void k_bscan(const int* __restrict__ bcount,
                                               int* __restrict__ bstart,
                                               int* __restrict__ bcur, int NB) {
    __shared__ int sh[256];
    int t = threadIdx.x;
    int base = t * 4;
    int v0 = (base + 0 < NB) ? bcount[base + 0] : 0;
    int v1 = (base + 1 < NB) ? bcount[base + 1] : 0;
    int v2 = (base + 2 < NB) ? bcount[base + 2] : 0;
    int v3 = (base + 3 < NB) ? bcount[base + 3] : 0;
    int s = v0 + v1 + v2 + v3;
    sh[t] = s;
    __syncthreads();
    for (int off = 1; off < 256; off <<= 1) {
        int xv = (t >= off) ? sh[t - off] : 0;
        __syncthreads();
        sh[t] += xv;
        __syncthreads();
    }
    int excl = sh[t] - s;
    int o0 = excl, o1 = excl + v0, o2 = excl + v0 + v1, o3 = excl + v0 + v1 + v2;
    if (base + 0 < NB) { bstart[base+0]=o0; bcur[base+0]=o0; }
    if (base + 1 < NB) { bstart[base+1]=o1; bcur[base+1]=o1; }
    if (base + 2 < NB) { bstart[base+2]=o2; bcur[base+2]=o2; }
    if (base + 3 < NB) { bstart[base+3]=o3; bcur[base+3]=o3; }
    if (t == 255) bstart[NB] = sh[255];
}

// ---------- phase 1: block-aggregated binning into bucket windows ----------
__global__ __launch_bounds__(256) void k_bin(const int* __restrict__ src,
                                             const int* __restrict__ dst,
                                             int* __restrict__ bcur,
                                             unsigned* __restrict__ tmp,
                                             int E, int NB) {
    __shared__ int hist[NBMAX];
    int t = threadIdx.x;
    int e0 = blockIdx.x * ECHUNK;
    int e1 = min(e0 + ECHUNK, E);
    for (int k = t; k < NB; k += 256) hist[k] = 0;
    __syncthreads();
    for (int e = e0 + t; e < e1; e += 256) atomicAdd(&hist[dst[e] >> 7], 1);
    __syncthreads();
    for (int k = t; k < NB; k += 256) {
        int c = hist[k];
        hist[k] = (c > 0) ? atomicAdd(&bcur[k], c) : 0;
    }
    __syncthreads();
    for (int e = e0 + t; e < e1; e += 256) {
        int s = src[e], d = dst[e];
        int p = atomicAdd(&hist[d >> 7], 1);
        tmp[p] = (unsigned)s | ((unsigned)(d & 127) << 17);
    }
}

// ---------- phase 2: per bucket — degrees, offs, dinv, xs, CSR order ----------
__global__ __launch_bounds__(256) void k_csrdeg(const unsigned* __restrict__ tmp,
                                                const int* __restrict__ bstart,
                                                const float* __restrict__ x,
                                                int* __restrict__ offs,
                                                float* __restrict__ dinv,
                                                float* __restrict__ xs,
                                                int* __restrict__ csr_src,
                                                int n, int E) {
    __shared__ int cnt[128];
    __shared__ int sc[128];
    __shared__ int cur[128];
    __shared__ int win[CAP];
    int b = blockIdx.x;
    int node0 = b << 7;
    int nn = min(128, n - node0);
    int t = threadIdx.x;
    int base = bstart[b];
    int count = bstart[b + 1] - base;

    if (t < 128) cnt[t] = 0;
    __syncthreads();
    for (int k = t; k < count; k += 256) atomicAdd(&cnt[tmp[base + k] >> 17], 1);
    __syncthreads();
    if (t < 128) sc[t] = (t < nn) ? cnt[t] : 0;
    __syncthreads();
    for (int off = 1; off < 128; off <<= 1) {
        int v = (t < 128 && t >= off) ? sc[t - off] : 0;
        __syncthreads();
        if (t < 128) sc[t] += v;
        __syncthreads();
    }
    if (t < nn) {
        int excl = sc[t] - cnt[t];
        offs[node0 + t] = base + excl;
        cur[t] = excl;
        float di = rsqrtf((float)(cnt[t] + 1));
        dinv[node0 + t] = di;
        xs[node0 + t] = di * x[node0 + t];
        if (node0 + t + 1 == n) offs[n] = E;
    }
    __syncthreads();
    if (count <= CAP) {
        for (int k = t; k < count; k += 256) {
            unsigned v = tmp[base + k];
            int p = atomicAdd(&cur[v >> 17], 1);
            win[p] = v & 0x1FFFF;
        }
        __syncthreads();
        for (int k = t; k < count; k += 256) csr_src[base + k] = win[k];
    } else {  // safety fallback
        for (int k = t; k < count; k += 256) {
            unsigned v = tmp[base + k];
            int p = atomicAdd(&cur[v >> 17], 1);
            csr_src[base + p] = v & 0x1FFFF;
        }
    }
}

// ---------- layer 0: scalar gather (x is [n,1]) + transform + pool + T1 ----------
__global__ __launch_bounds__(256) void k_layer0(
        const float* __restrict__ xs, unsigned* __restrict__ Tout,
        const int* __restrict__ offs, const int* __restrict__ csr_src,
        const float* __restrict__ dinv, const float* __restrict__ b1,
        const float* __restrict__ W1, const float* __restrict__ W2,
        const int* __restrict__ batch, float* __restrict__ pooled, int n) {
    __shared__ float hred[16][HID];
    __shared__ float wsh[HID * HID];
    __shared__ int gid[16];
    int t = threadIdx.x;
    int il = t >> 4, jp = t & 15;
    int node = blockIdx.x * 16 + il;
    bool valid = node < n;

    for (int k = t; k < HID * HID; k += 256) wsh[k] = W2[k];

    float a = 0.f, di = 0.f;
    if (valid) {
        int s0 = offs[node], s1 = offs[node + 1];
        for (int k = s0 + jp; k < s1; k += 16) a += xs[csr_src[k]];
    }
    for (int d = 1; d < 16; d <<= 1) a += __shfl_xor(a, d, 16);
    float lo = 0.f, hi = 0.f;
    if (valid) {
        di = dinv[node];
        float tot = di * (a + xs[node]);  // + self loop
        lo = fmaxf(tot * W1[2 * jp] + b1[2 * jp], 0.f);
        hi = fmaxf(tot * W1[2 * jp + 1] + b1[2 * jp + 1], 0.f);
    }
    hred[il][2 * jp] = lo;
    hred[il][2 * jp + 1] = hi;
    if (jp == 0) gid[il] = valid ? batch[node] : -1;
    __syncthreads();

    if (t < HID) {
        float run = 0.f;
        int g = gid[0];
#pragma unroll
        for (int nn = 0; nn < 16; ++nn) {
            int gn = gid[nn];
            if (gn != g) {
                if (g >= 0) atomicAdd(&pooled[g * POOLW + t], run);
                run = 0.f;
                g = gn;
            }
            run += hred[nn][t];
        }
        if (g >= 0) atomicAdd(&pooled[g * POOLW + t], run);
    }

    if (valid) {
        float al = 0.f, ah = 0.f;
#pragma unroll
        for (int k2 = 0; k2 < HID; ++k2) {
            float hh = hred[il][k2];
            al += hh * wsh[k2 * HID + 2 * jp];
            ah += hh * wsh[k2 * HID + 2 * jp + 1];
        }
        union { bf16 b[2]; unsigned u; } pk;
        pk.b[0] = __float2bfloat16(di * al);
        pk.b[1] = __float2bfloat16(di * ah);
        Tout[node * HIDW + jp] = pk.u;
    }
}

// ---------- fused layer (1..5): preloaded-index gather + pool + next T ----------
// 16 nodes per 256-thread block; 16 lanes per node, 2 dims (bf16x2) per lane.
// 32 edge indices preloaded via 2 coalesced loads + shfl distribution:
// one csr-latency round + one gather round per node (no chained rounds).
__global__ __launch_bounds__(256) void k_layer(
        const unsigned* __restrict__ Tin, unsigned* __restrict__ Tout,
        const int* __restrict__ offs, const int* __restrict__ csr_src,
        const float* __restrict__ dinv, const float* __restrict__ bias,
        const float* __restrict__ Wnext, const int* __restrict__ batch,
        float* __restrict__ pooled, int n, int layer, int last) {
    __shared__ float hred[16][HID];
    __shared__ float wsh[HID * HID];
    __shared__ int gid[16];
    int t = threadIdx.x;
    int il = t >> 4, jp = t & 15;
    int node = blockIdx.x * 16 + il;
    bool valid = node < n;

    if (!last) {
        for (int k = t; k < HID * HID; k += 256) wsh[k] = Wnext[k];
    }

    float lo = 0.f, hi = 0.f, di = 0.f;
    if (valid) {
        di = dinv[node];
        unsigned w = Tin[node * HIDW + jp];  // self loop
        float l0 = bf_lo(w), h0 = bf_hi(w);
        float l1 = 0, h1 = 0, l2 = 0, h2 = 0, l3 = 0, h3 = 0;
        float l4 = 0, h4 = 0, l5 = 0, h5 = 0, l6 = 0, h6 = 0, l7 = 0, h7 = 0;
        int s0 = offs[node], s1 = offs[node + 1];
        int deg = s1 - s0;
        // coalesced index preload (csr_src padded by 64)
        int iA = (jp < deg) ? csr_src[s0 + jp] : n;
        int iB = (jp + 16 < deg) ? csr_src[s0 + 16 + jp] : n;
        float* lp[8] = {&l0, &l1, &l2, &l3, &l4, &l5, &l6, &l7};
        float* hp[8] = {&h0, &h1, &h2, &h3, &h4, &h5, &h6, &h7};
#pragma unroll
        for (int i = 0; i < 16; ++i) {
            int idx = __shfl(iA, i, 16);
            unsigned wv = Tin[idx * HIDW + jp];
            *lp[i & 7] += bf_lo(wv);
            *hp[i & 7] += bf_hi(wv);
        }
        if (deg > 16) {  // group-uniform; exec-masked when off
#pragma unroll
            for (int i = 0; i < 16; ++i) {
                int idx = __shfl(iB, i, 16);
                unsigned wv = Tin[idx * HIDW + jp];
                *lp[i & 7] += bf_lo(wv);
                *hp[i & 7] += bf_hi(wv);
            }
        }
        for (int k = s0 + 32; k < s1; ++k) {  // rare tail (P(deg>32) ~ 1e-4)
            unsigned wv = Tin[csr_src[k] * HIDW + jp];
            l0 += bf_lo(wv); h0 += bf_hi(wv);
        }
        float accl = ((l0 + l1) + (l2 + l3)) + ((l4 + l5) + (l6 + l7));
        float acch = ((h0 + h1) + (h2 + h3)) + ((h4 + h5) + (h6 + h7));
        lo = fmaxf(di * accl + bias[2 * jp], 0.f);
        hi = fmaxf(di * acch + bias[2 * jp + 1], 0.f);
    }
    hred[il][2 * jp] = lo;
    hred[il][2 * jp + 1] = hi;
    if (jp == 0) gid[il] = valid ? batch[node] : -1;
    __syncthreads();

    // pooling: segmented reduce over the block's 16 (sorted-batch) nodes
    if (t < HID) {
        float run = 0.f;
        int g = gid[0];
#pragma unroll
        for (int nn = 0; nn < 16; ++nn) {
            int gn = gid[nn];
            if (gn != g) {
                if (g >= 0) atomicAdd(&pooled[g * POOLW + layer * HID + t], run);
                run = 0.f;
                g = gn;
            }
            run += hred[nn][t];
        }
        if (g >= 0) atomicAdd(&pooled[g * POOLW + layer * HID + t], run);
    }

    // next-layer transform (2 output dims per lane), packed bf16x2 store
    if (!last && valid) {
        float al = 0.f, ah = 0.f;
#pragma unroll
        for (int k2 = 0; k2 < HID; ++k2) {
            float hh = hred[il][k2];
            al += hh * wsh[k2 * HID + 2 * jp];
            ah += hh * wsh[k2 * HID + 2 * jp + 1];
        }
        union { bf16 b[2]; unsigned u; } pk;
        pk.b[0] = __float2bfloat16(di * al);
        pk.b[1] = __float2bfloat16(di * ah);
        Tout[node * HIDW + jp] = pk.u;
    }
}

// ---------- head: fc1(192->128) + relu + fc2(128->2) + softmax ----------
__global__ __launch_bounds__(128) void k_mlp(const float* __restrict__ pooled,
                                             const float* __restrict__ fc1_w,
                                             const float* __restrict__ fc1_b,
                                             const float* __restrict__ fc2_w,
                                             const float* __restrict__ fc2_b,
                                             float* __restrict__ out, int G) {
    __shared__ float z[POOLW];
    __shared__ float w0s[2], w1s[2];
    int g = blockIdx.x;
    int t = threadIdx.x;
    for (int k = t; k < POOLW; k += 128) z[k] = pooled[g * POOLW + k];
    __syncthreads();
    float a = fc1_b[t];
    for (int k = 0; k < POOLW; ++k) a += z[k] * fc1_w[k * 128 + t];
    float z1 = fmaxf(a, 0.f);
    float p0 = z1 * fc2_w[t * 2 + 0];
    float p1 = z1 * fc2_w[t * 2 + 1];
    for (int off = 32; off >= 1; off >>= 1) {
        p0 += __shfl_down(p0, off, 64);
        p1 += __shfl_down(p1, off, 64);
    }
    if ((t & 63) == 0) { w0s[t >> 6] = p0; w1s[t >> 6] = p1; }
    __syncthreads();
    if (t == 0) {
        float o0 = w0s[0] + w0s[1] + fc2_b[0];
        float o1 = w1s[0] + w1s[1] + fc2_b[1];
        float m = fmaxf(o0, o1);
        float e0 = expf(o0 - m), e1 = expf(o1 - m);
        float s = e0 + e1;
        out[g * 2 + 0] = e0 / s;
        out[g * 2 + 1] = e1 / s;
    }
}

extern "C" void kernel_launch(void* const* d_in, const int* in_sizes, int n_in,
                              void* d_out, int out_size, void* d_ws, size_t ws_size,
                              hipStream_t stream) {
    const float* x     = (const float*)d_in[0];
    const int*   ei    = (const int*)d_in[1];
    const int*   batch = (const int*)d_in[2];
    const float* Ws[6] = {(const float*)d_in[3], (const float*)d_in[5],
                          (const float*)d_in[7], (const float*)d_in[9],
                          (const float*)d_in[11], (const float*)d_in[13]};
    const float* bs[6] = {(const float*)d_in[4], (const float*)d_in[6],
                          (const float*)d_in[8], (const float*)d_in[10],
                          (const float*)d_in[12], (const float*)d_in[14]};
    const float* fc1_w = (const float*)d_in[15];
    const float* fc1_b = (const float*)d_in[16];
    const float* fc2_w = (const float*)d_in[17];
    const float* fc2_b = (const float*)d_in[18];

    int n = in_sizes[0];       // 100000
    int E = in_sizes[1] / 2;   // 1600000
    int G = out_size / 2;      // 256
    const int* src = ei;
    const int* dst = ei + E;
    int NB = (n + 127) / 128;  // buckets (782)

    char* p = (char*)d_ws;
    auto alloc = [&](size_t bytes) -> void* {
        void* r = (void*)p;
        p += (bytes + 255) / 256 * 256;
        return r;
    };
    int*      bcount  = (int*)alloc((size_t)NB * 4);
    int*      bstart  = (int*)alloc((size_t)(NB + 1) * 4);
    int*      bcur    = (int*)alloc((size_t)NB * 4);
    int*      offs    = (int*)alloc((size_t)(n + 1) * 4);
    float*    dinv    = (float*)alloc((size_t)n * 4);
    float*    xs      = (float*)alloc((size_t)n * 4);
    unsigned* tmp     = (unsigned*)alloc((size_t)E * 4);
    int*      csr_src = (int*)alloc((size_t)(E + 64) * 4);  // padded for masked loads
    unsigned* Ta      = (unsigned*)alloc((size_t)(n + 1) * HIDW * 4);  // row n = zero
    unsigned* Tb      = (unsigned*)alloc((size_t)(n + 1) * HIDW * 4);  // row n = zero
    float*    pooled  = (float*)alloc((size_t)G * POOLW * 4);

    hipMemsetAsync(bcount, 0, (size_t)NB * 4, stream);
    hipMemsetAsync(pooled, 0, (size_t)G * POOLW * 4, stream);
    hipMemsetAsync(Ta + (size_t)n * HIDW, 0, HIDW * 4, stream);
    hipMemsetAsync(Tb + (size_t)n * HIDW, 0, HIDW * 4, stream);

    int nbE = (E + ECHUNK - 1) / ECHUNK;
    k_bcount<<<nbE, 256, 0, stream>>>(dst, bcount, E, NB);
    k_bscan<<<1, 256, 0, stream>>>(bcount, bstart, bcur, NB);
    k_bin<<<nbE, 256, 0, stream>>>(src, dst, bcur, tmp, E, NB);
    k_csrdeg<<<NB, 256, 0, stream>>>(tmp, bstart, x, offs, dinv, xs, csr_src, n, E);

    int nblk16 = (n + 15) / 16;
    // layer 0: scalar gather, writes T for layer 1 into Tb, pools slot 0
    k_layer0<<<nblk16, 256, 0, stream>>>(xs, Tb, offs, csr_src, dinv, bs[0],
                                         Ws[0], Ws[1], batch, pooled, n);
    unsigned* Tin = Tb;
    unsigned* Tout = Ta;
    for (int l = 1; l < 6; ++l) {
        int last = (l == 5);
        k_layer<<<nblk16, 256, 0, stream>>>(Tin, Tout, offs, csr_src, dinv, bs[l],
                                            last ? nullptr : Ws[l + 1], batch,
                                            pooled, n, l, last);
        unsigned* t2 = Tin; Tin = Tout; Tout = t2;
    }
    k_mlp<<<G, 128, 0, stream>>>(pooled, fc1_w, fc1_b, fc2_w, fc2_b, (float*)d_out, G);
}